// Round 14
// baseline (255.407 us; speedup 1.0000x reference)
//
#include <hip/hip_runtime.h>
#include <hip/hip_bf16.h>
#include <math.h>

#define NB 32768      // total nodes (B*N)
#define NN 2048       // nodes per graph
#define BG 16         // graphs
#define KK 1639       // kept per graph (0.8*2048 ceil)
#define KKP 1664      // kept rows padded (52*32)
#define N1 (BG*KK)    // 26224 real kept nodes
#define N1P (BG*KKP)  // 26624 padded kept rows
#define EE 524288     // total edges
#define HH 128        // hidden
#define FIN 64        // input features

using half8 = __attribute__((ext_vector_type(8))) _Float16;
using half4 = __attribute__((ext_vector_type(4))) _Float16;
using f32x4 = __attribute__((ext_vector_type(4))) float;

__device__ __forceinline__ void acc4(f32x4& a, const float4& v) {
  a[0] += v.x; a[1] += v.y; a[2] += v.z; a[3] += v.w;
}

// ---------------- CSR build (layer-1 graph only) ----------------
__global__ void deg_kernel(const int* __restrict__ dst, int* deg, int n) {
  int e = blockIdx.x * blockDim.x + threadIdx.x;
  if (e < n) atomicAdd(&deg[dst[e]], 1);
}

// single-block coalesced exclusive scan (int4 tiles of 4096); deg must be padded.
__global__ void exscan_kernel(const int* __restrict__ deg, int* rs, int* cursor, int n) {
  __shared__ int wsum[16];
  __shared__ int carry;
  int t = threadIdx.x;  // 1024
  int lane = t & 63, wid = t >> 6;
  if (t == 0) carry = 0;
  __syncthreads();
  int ntiles = (n + 4095) >> 12;
  for (int tile = 0; tile < ntiles; ++tile) {
    int idx = (tile << 12) + t * 4;
    int4 v4 = *(const int4*)(deg + idx);
    int v0 = (idx + 0 < n) ? v4.x : 0;
    int v1 = (idx + 1 < n) ? v4.y : 0;
    int v2 = (idx + 2 < n) ? v4.z : 0;
    int v3 = (idx + 3 < n) ? v4.w : 0;
    int s = v0 + v1 + v2 + v3;
    int pre = s;
#pragma unroll
    for (int off = 1; off < 64; off <<= 1) {
      int u = __shfl_up(pre, off, 64);
      if (lane >= off) pre += u;
    }
    if (lane == 63) wsum[wid] = pre;
    __syncthreads();
    int wbase = 0;
#pragma unroll
    for (int ww = 0; ww < 16; ++ww)
      if (ww < wid) wbase += wsum[ww];
    int ex = carry + wbase + (pre - s);
    int4 e4 = make_int4(ex, ex + v0, ex + v0 + v1, ex + v0 + v1 + v2);
    if (idx + 3 < n) {
      *(int4*)(rs + idx) = e4;
      *(int4*)(cursor + idx) = e4;
    } else {
      if (idx + 0 < n) { rs[idx + 0] = e4.x; cursor[idx + 0] = e4.x; }
      if (idx + 1 < n) { rs[idx + 1] = e4.y; cursor[idx + 1] = e4.y; }
      if (idx + 2 < n) { rs[idx + 2] = e4.z; cursor[idx + 2] = e4.z; }
    }
    int tot = 0;
    if (t == 1023) tot = ex + s;
    __syncthreads();
    if (t == 1023) carry = tot;
    __syncthreads();
  }
  if (t == 0) rs[n] = carry;
}

__global__ void scatter_kernel(const int* __restrict__ src, const int* __restrict__ dst,
                               int* cursor, int* csr, int n) {
  int e = blockIdx.x * blockDim.x + threadIdx.x;
  if (e < n) {
    int d = dst[e];
    int p = atomicAdd(&cursor[d], 1);
    csr[p] = src[e];
  }
}

// ---------------- fused agg + conv GEMM (+optional pool / score epilogues) ----------------
// 32-ROW TILE: 512 thr = 8 waves; tile = 32 rows x 128 cols; wave = 32x16 (2 row frags).
// LDS = 2 planes x 32 x KTOT f16 (32KB @KTOT=256) -> 4 blocks/CU, 32 waves (full occ)
// to maximize outstanding gather requests (gather is L2-latency-bound).
// Phase 1a: wave-coalesced CSR gather (4 rows/wave, 8 edge-batches in flight).
//   REMAP=1 (conv3): row -> perm -> CSR1 edges; src kept iff new_id[src]>=0.
// Phase 1b: root staging. Phase 2: ds_read + MFMA, W double-buffered from L2.
// POOL=1: x1 partials (64 slices of 32). POOL=2: x3 partials (52 slices, >=KK masked).
// SCORE=1: per-row tanh(dot(h,w)/||w||).
template <int KD1, int KD2, int POOL, int SCORE, int REMAP>
__global__ __launch_bounds__(512, 4) void conv_mfma(
    const float* __restrict__ feat, const float* __restrict__ xr,
    const int* __restrict__ rs, const int* __restrict__ csr,
    const int* __restrict__ perm, const int* __restrict__ new_id,
    const _Float16* __restrict__ Wh, const _Float16* __restrict__ Wl,
    const float* __restrict__ bias, float* __restrict__ out, int M, int nwg,
    float* __restrict__ pmax, float* __restrict__ psum,
    const float* __restrict__ pw, float* __restrict__ score) {
  constexpr int KTOT = KD1 + KD2;
  constexpr int NSTEP = KTOT / 32;
  __shared__ _Float16 ah_lds[32 * KTOT];
  __shared__ _Float16 al_lds[32 * KTOT];
  __shared__ float sdot[32][8];
  __shared__ float swsq[8];

  int tid = threadIdx.x;
  int lane = tid & 63, wid = tid >> 6;
  // bijective XCD-chunk swizzle (m204)
  int bq = nwg >> 3, br = nwg & 7, bx = blockIdx.x & 7, bi = blockIdx.x >> 3;
  int swz = (bx < br ? bx * (bq + 1) : br * (bq + 1) + (bx - br) * bq) + bi;
  int row0 = swz * 32;
  int ch0 = wid * 16;
  int col = lane & 15;
  int kseg = (lane >> 4) * 8;

  // ---- Phase 1a: wave-coalesced CSR gather (k in [0, KD1)), 8-deep MLP ----
  {
    constexpr int CH = KD1 / 4;     // f4 chunks per row (16 or 32)
    constexpr int EPW = 64 / CH;    // edges per wave step (4 or 2)
    int sub = lane / CH;
    int ch = lane % CH;
    const float4* feat4 = (const float4*)feat;
#pragma unroll
    for (int rr = 0; rr < 4; ++rr) {
      int gr = wid * 4 + rr;
      int grow = row0 + gr;
      int e0 = 0, e1 = 0;
      if (REMAP) {
        int g = grow / KKP, j = grow - g * KKP;
        if (j < KK) {
          int oldrow = perm[g * KK + j];
          e0 = rs[oldrow];
          e1 = rs[oldrow + 1];
        }
      } else {
        if (grow >= M) grow = M - 1;
        e0 = rs[grow];
        e1 = rs[grow + 1];
      }
      f32x4 a0 = {0.f, 0.f, 0.f, 0.f}, a1 = a0, a2 = a0, a3 = a0;
      int e = e0 + sub;
      for (; e + 7 * EPW < e1; e += 8 * EPW) {
        int c[8];
#pragma unroll
        for (int u = 0; u < 8; ++u) c[u] = csr[e + u * EPW];
        if (REMAP) {
#pragma unroll
          for (int u = 0; u < 8; ++u) c[u] = new_id[c[u]];
        }
        float4 v[8];
#pragma unroll
        for (int u = 0; u < 8; ++u) {
          int ci = (REMAP && c[u] < 0) ? 0 : c[u];
          v[u] = feat4[(size_t)ci * CH + ch];
        }
        if (REMAP) {
#pragma unroll
          for (int u = 0; u < 8; ++u)
            if (c[u] < 0) v[u] = make_float4(0.f, 0.f, 0.f, 0.f);
        }
        acc4(a0, v[0]); acc4(a1, v[1]); acc4(a2, v[2]); acc4(a3, v[3]);
        acc4(a0, v[4]); acc4(a1, v[5]); acc4(a2, v[6]); acc4(a3, v[7]);
      }
      for (; e + 3 * EPW < e1; e += 4 * EPW) {
        int c[4];
#pragma unroll
        for (int u = 0; u < 4; ++u) c[u] = csr[e + u * EPW];
        if (REMAP) {
#pragma unroll
          for (int u = 0; u < 4; ++u) c[u] = new_id[c[u]];
        }
        float4 v[4];
#pragma unroll
        for (int u = 0; u < 4; ++u) {
          int ci = (REMAP && c[u] < 0) ? 0 : c[u];
          v[u] = feat4[(size_t)ci * CH + ch];
        }
        if (REMAP) {
#pragma unroll
          for (int u = 0; u < 4; ++u)
            if (c[u] < 0) v[u] = make_float4(0.f, 0.f, 0.f, 0.f);
        }
        acc4(a0, v[0]); acc4(a1, v[1]); acc4(a2, v[2]); acc4(a3, v[3]);
      }
      for (; e < e1; e += EPW) {
        int c = csr[e];
        if (REMAP) {
          c = new_id[c];
          if (c < 0) continue;
        }
        float4 v = feat4[(size_t)c * CH + ch];
        acc4(a0, v);
      }
      f32x4 s = (a0 + a1) + (a2 + a3);
      if (EPW == 4) {
#pragma unroll
        for (int j = 0; j < 4; ++j) s[j] += __shfl_xor(s[j], 16, 64);
      }
#pragma unroll
      for (int j = 0; j < 4; ++j) s[j] += __shfl_xor(s[j], 32, 64);
      if (sub == 0) {
        half4 hi, lo;
#pragma unroll
        for (int j = 0; j < 4; ++j) {
          _Float16 h = (_Float16)s[j];
          hi[j] = h;
          lo[j] = (_Float16)(s[j] - (float)h);
        }
        int byte = ((gr * KTOT + ch * 4) * 2) ^ ((gr & 7) << 4);
        *(half4*)((char*)ah_lds + byte) = hi;
        *(half4*)((char*)al_lds + byte) = lo;
      }
    }
  }

  // ---- Phase 1b: root staging (k in [KD1, KTOT)) ----
  for (int idx = tid; idx < 32 * KD2 / 8; idx += 512) {
    int row = idx / (KD2 / 8);
    int kc = (idx % (KD2 / 8)) * 8;
    int grow = row0 + row;
    if (grow >= M) grow = M - 1;
    const float* sp = xr + (size_t)grow * KD2 + kc;
    float4 a0 = *(const float4*)sp;
    float4 a1 = *(const float4*)(sp + 4);
    float av[8] = {a0.x, a0.y, a0.z, a0.w, a1.x, a1.y, a1.z, a1.w};
    half8 vh, vl;
#pragma unroll
    for (int j = 0; j < 8; ++j) {
      _Float16 h = (_Float16)av[j];
      vh[j] = h;
      vl[j] = (_Float16)(av[j] - (float)h);
    }
    int byte = ((row * KTOT + KD1 + kc) * 2) ^ ((row & 7) << 4);
    *(half8*)((char*)ah_lds + byte) = vh;
    *(half8*)((char*)al_lds + byte) = vl;
  }

  // issue first W step before the barrier
  size_t wbase = (size_t)(ch0 + col) * KTOT + kseg;
  half8 whc = *(const half8*)(Wh + wbase);
  half8 wlc = *(const half8*)(Wl + wbase);
  __syncthreads();

  // ---- Phase 2: k-loop; W double-buffered from L2, A from LDS ----
  f32x4 acc[2];
#pragma unroll
  for (int rf = 0; rf < 2; ++rf) acc[rf] = (f32x4){0.f, 0.f, 0.f, 0.f};
  int r = lane & 15;
#pragma unroll
  for (int s = 0; s < NSTEP; ++s) {
    half8 whn, wln;
    if (s + 1 < NSTEP) {
      whn = *(const half8*)(Wh + wbase + (s + 1) * 32);
      wln = *(const half8*)(Wl + wbase + (s + 1) * 32);
    }
#pragma unroll
    for (int rf = 0; rf < 2; ++rf) {
      int row = rf * 16 + r;
      int byte = ((row * KTOT + s * 32 + kseg) * 2) ^ ((row & 7) << 4);
      half8 a_h = *(const half8*)((const char*)ah_lds + byte);
      half8 a_l = *(const half8*)((const char*)al_lds + byte);
      acc[rf] = __builtin_amdgcn_mfma_f32_16x16x32_f16(a_l, whc, acc[rf], 0, 0, 0);
      acc[rf] = __builtin_amdgcn_mfma_f32_16x16x32_f16(a_h, wlc, acc[rf], 0, 0, 0);
      acc[rf] = __builtin_amdgcn_mfma_f32_16x16x32_f16(a_h, whc, acc[rf], 0, 0, 0);
    }
    if (s + 1 < NSTEP) { whc = whn; wlc = wln; }
  }

  // ---- epilogue: bias + relu (+ pool partials / score) ----
  float bv = bias[ch0 + col];
  float cmax = -3.402823466e38f, csum = 0.f;
  float wcol = SCORE ? pw[ch0 + col] : 0.f;
  float pd[2][4];
  int g = 0, rowbase = 0;
  if (POOL == 2) { g = row0 / KKP; rowbase = row0 - g * KKP; }
#pragma unroll
  for (int rf = 0; rf < 2; ++rf) {
    int orow0 = row0 + rf * 16 + (lane >> 4) * 4;
#pragma unroll
    for (int rr = 0; rr < 4; ++rr) {
      int orow = orow0 + rr;
      float v = fmaxf(acc[rf][rr] + bv, 0.f);
      if (orow < M) out[(size_t)orow * HH + ch0 + col] = v;
      if (POOL == 1) { cmax = fmaxf(cmax, v); csum += v; }
      if (POOL == 2) {
        int local = rowbase + rf * 16 + (lane >> 4) * 4 + rr;
        if (local < KK) { cmax = fmaxf(cmax, v); csum += v; }
      }
      if (SCORE) pd[rf][rr] = v * wcol;
    }
  }
  if (POOL) {
    cmax = fmaxf(cmax, __shfl_xor(cmax, 16, 64)); csum += __shfl_xor(csum, 16, 64);
    cmax = fmaxf(cmax, __shfl_xor(cmax, 32, 64)); csum += __shfl_xor(csum, 32, 64);
    if ((lane >> 4) == 0) {
      if (POOL == 1) {
        int gg = row0 >> 11, sb = (row0 & 2047) >> 5;  // 64 slices of 32 rows
        pmax[(gg * 64 + sb) * HH + ch0 + col] = cmax;
        psum[(gg * 64 + sb) * HH + ch0 + col] = csum;
      } else {
        int sb = rowbase >> 5;                          // 52 slices of 32 rows
        pmax[(g * 52 + sb) * HH + ch0 + col] = cmax;
        psum[(g * 52 + sb) * HH + ch0 + col] = csum;
      }
    }
  }
  if (SCORE) {
#pragma unroll
    for (int rf = 0; rf < 2; ++rf)
#pragma unroll
      for (int rr = 0; rr < 4; ++rr) {
        float d = pd[rf][rr];
        d += __shfl_xor(d, 1, 64); d += __shfl_xor(d, 2, 64);
        d += __shfl_xor(d, 4, 64); d += __shfl_xor(d, 8, 64);
        if (col == 0) sdot[rf * 16 + (lane >> 4) * 4 + rr][wid] = d;
      }
    float wsq = wcol * wcol;
    wsq += __shfl_xor(wsq, 1, 64); wsq += __shfl_xor(wsq, 2, 64);
    wsq += __shfl_xor(wsq, 4, 64); wsq += __shfl_xor(wsq, 8, 64);
    if (lane == 0) swsq[wid] = wsq;
    __syncthreads();
    if (tid < 32) {
      float d = 0.f, q = 0.f;
#pragma unroll
      for (int wv = 0; wv < 8; ++wv) { d += sdot[tid][wv]; q += swsq[wv]; }
      score[row0 + tid] = tanhf(d * rsqrtf(q));
    }
  }
}

// ---------------- weight prep: split Wcat[o][k] into f16 hi + lo planes ----------------
__global__ void prep_weights_f16(const float* __restrict__ W1_rel, const float* __restrict__ W1_root,
                                 const float* __restrict__ W2_rel, const float* __restrict__ W2_root,
                                 const float* __restrict__ W3_rel, const float* __restrict__ W3_root,
                                 _Float16* wh1, _Float16* wl1, _Float16* wh2, _Float16* wl2,
                                 _Float16* wh3, _Float16* wl3) {
  int idx = blockIdx.x * blockDim.x + threadIdx.x;
  float v;
  _Float16* ph;
  _Float16* pl;
  int j;
  if (idx < 128 * 128) {
    j = idx;
    int o = j >> 7, k = j & 127;
    v = (k < 64) ? W1_rel[o * 64 + k] : W1_root[o * 64 + (k - 64)];
    ph = wh1; pl = wl1;
  } else if (idx < 128 * 128 + 128 * 256) {
    j = idx - 128 * 128;
    int o = j >> 8, k = j & 255;
    v = (k < 128) ? W2_rel[o * 128 + k] : W2_root[o * 128 + (k - 128)];
    ph = wh2; pl = wl2;
  } else if (idx < 128 * 128 + 2 * 128 * 256) {
    j = idx - 128 * 128 - 128 * 256;
    int o = j >> 8, k = j & 255;
    v = (k < 128) ? W3_rel[o * 128 + k] : W3_root[o * 128 + (k - 128)];
    ph = wh3; pl = wl3;
  } else {
    return;
  }
  _Float16 h = (_Float16)v;
  ph[j] = h;
  pl[j] = (_Float16)(v - (float)h);
}

// ---------------- topk via radix-select (keys distinct -> exact set) ----------------
// Output order is arbitrary (downstream is order-invariant); 256 thr/block, 1 block/graph.
__global__ void topk_kernel(const float* __restrict__ score, int* perm) {
  __shared__ unsigned long long keys[NN];
  __shared__ int hist[256];
  __shared__ unsigned long long sP;
  __shared__ int srem;
  __shared__ int scnt;
  int b = blockIdx.x, t = threadIdx.x;  // 256 threads
  for (int i = t; i < NN; i += 256) {
    float s = score[b * NN + i];
    unsigned u = __float_as_uint(s);
    u = (u & 0x80000000u) ? ~u : (u | 0x80000000u);
    keys[i] = ((unsigned long long)u << 32) | (unsigned)(NN - 1 - i);
  }
  if (t == 0) { sP = 0ULL; srem = KK; scnt = 0; }
  __syncthreads();
  for (int pass = 0; pass < 8; ++pass) {
    int shift = 56 - 8 * pass;
    for (int i = t; i < 256; i += 256) hist[i] = 0;
    __syncthreads();
    unsigned long long P = sP;
    unsigned long long hm = (pass == 0) ? 0ULL : (~0ULL) << (shift + 8);
    for (int i = t; i < NN; i += 256) {
      unsigned long long k = keys[i];
      if (((k ^ P) & hm) == 0) atomicAdd(&hist[(int)((k >> shift) & 255)], 1);
    }
    __syncthreads();
    if (t < 64) {
      int l = t;
      int c[4], part = 0;
#pragma unroll
      for (int q = 0; q < 4; ++q) { c[q] = hist[255 - (l * 4 + q)]; part += c[q]; }
      int pre = part;
#pragma unroll
      for (int off = 1; off < 64; off <<= 1) {
        int u2 = __shfl_up(pre, off, 64);
        if (l >= off) pre += u2;
      }
      int excl = pre - part;
      int rem = srem;
      if (excl < rem && rem <= excl + part) {
        int run = excl;
#pragma unroll
        for (int q = 0; q < 4; ++q) {
          if (run + c[q] >= rem) {
            srem = rem - run;
            sP = sP | ((unsigned long long)(255 - (l * 4 + q)) << shift);
            break;
          }
          run += c[q];
        }
      }
    }
    __syncthreads();
  }
  unsigned long long T = sP;  // key of the K-th largest element (exact)
  for (int i = t; i < NN; i += 256) {
    if (keys[i] >= T) {
      int pos = atomicAdd(&scnt, 1);
      perm[b * KK + pos] = b * NN + (NN - 1 - (int)(keys[i] & 0xffffffffULL));
    }
  }
}

// gather kept rows (f4), scale by score, write new_id (padded id space)
__global__ void h3_kernel(const float4* __restrict__ h2, const int* __restrict__ perm,
                          const float* __restrict__ score, float4* __restrict__ h3,
                          int* __restrict__ new_id) {
  int idx = blockIdx.x * blockDim.x + threadIdx.x;  // over N1*32 float4s
  if (idx < N1 * 32) {
    int g = idx >> 5, c = idx & 31;
    int b = g / KK, j = g - b * KK;
    int p = perm[g];
    if (c == 0) new_id[p] = b * KKP + j;
    float s = score[p];
    float4 v = h2[(size_t)p * 32 + c];
    v.x *= s; v.y *= s; v.z *= s; v.w *= s;
    h3[(size_t)(b * KKP + j) * 32 + c] = v;
  }
}

// x2 pool partials over padded h3 layout: BG x 26 slices of 64 rows (<KK masked)
__global__ void pool2_kernel(const float* __restrict__ h, float* pmax, float* psum) {
  int b = blockIdx.x / 26, s = blockIdx.x % 26;
  int f = threadIdx.x;
  int r0 = s * 64, r1 = min(KK, r0 + 64);
  float m = -3.402823466e38f, sum = 0.f;
  for (int r = r0; r < r1; ++r) {
    float v = h[(size_t)(b * KKP + r) * HH + f];
    m = fmaxf(m, v);
    sum += v;
  }
  pmax[(b * 26 + s) * HH + f] = m;
  psum[(b * 26 + s) * HH + f] = sum;
}

// ---------------- final: pool-final x3 + MLP + log_softmax ----------------
__global__ void mlp_kernel(const float* __restrict__ pm1, const float* __restrict__ ps1,
                           const float* __restrict__ pm2, const float* __restrict__ ps2,
                           const float* __restrict__ pm3, const float* __restrict__ ps3,
                           const float* __restrict__ Wl1, const float* __restrict__ bl1,
                           const float* __restrict__ Wl2, const float* __restrict__ bl2,
                           const float* __restrict__ Wl3, const float* __restrict__ bl3,
                           float* out) {
  __shared__ float z[256], a1[128], a2[64], a3[10], red[2];
  int b = blockIdx.x, t = threadIdx.x;  // 128 threads
  float m1 = -3.402823466e38f, m2 = m1, m3 = m1;
  float s1 = 0.f, s2 = 0.f, s3 = 0.f;
  for (int s = 0; s < 64; ++s) {  // x1: 64 slices of 32 (conv1 fused pool)
    int o = (b * 64 + s) * 128 + t;
    m1 = fmaxf(m1, pm1[o]); s1 += ps1[o];
  }
  for (int s = 0; s < 26; ++s) {  // x2: 26 slices
    int o = (b * 26 + s) * 128 + t;
    m2 = fmaxf(m2, pm2[o]); s2 += ps2[o];
  }
  for (int s = 0; s < 52; ++s) {  // x3: 52 slices of 32 (conv3 fused pool)
    int o = (b * 52 + s) * 128 + t;
    m3 = fmaxf(m3, pm3[o]); s3 += ps3[o];
  }
  z[t] = m1 + m2 + m3;
  z[128 + t] = s1 * (1.f / NN) + (s2 + s3) * (1.f / KK);
  __syncthreads();
  {
    float acc = bl1[t];
    for (int q = 0; q < 256; ++q) acc = fmaf(Wl1[t * 256 + q], z[q], acc);
    a1[t] = fmaxf(acc, 0.f);
  }
  __syncthreads();
  if (t < 64) {
    float acc = bl2[t];
    for (int q = 0; q < 128; ++q) acc = fmaf(Wl2[t * 128 + q], a1[q], acc);
    a2[t] = fmaxf(acc, 0.f);
  }
  __syncthreads();
  if (t < 10) {
    float acc = bl3[t];
    for (int q = 0; q < 64; ++q) acc = fmaf(Wl3[t * 64 + q], a2[q], acc);
    a3[t] = acc;
  }
  __syncthreads();
  if (t == 0) {
    float m = a3[0];
    for (int i = 1; i < 10; ++i) m = fmaxf(m, a3[i]);
    float s = 0.f;
    for (int i = 0; i < 10; ++i) s += expf(a3[i] - m);
    red[0] = m;
    red[1] = logf(s);
  }
  __syncthreads();
  if (t < 10) out[b * 10 + t] = a3[t] - red[0] - red[1];
}

extern "C" void kernel_launch(void* const* d_in, const int* in_sizes, int n_in,
                              void* d_out, int out_size, void* d_ws, size_t ws_size,
                              hipStream_t stream) {
  const float* x       = (const float*)d_in[0];
  const int*   src     = (const int*)d_in[1];
  const int*   dst     = (const int*)d_in[2];
  const float* W1_rel  = (const float*)d_in[3];
  const float* b1      = (const float*)d_in[4];
  const float* W1_root = (const float*)d_in[5];
  const float* W2_rel  = (const float*)d_in[6];
  const float* b2      = (const float*)d_in[7];
  const float* W2_root = (const float*)d_in[8];
  const float* W3_rel  = (const float*)d_in[9];
  const float* b3      = (const float*)d_in[10];
  const float* W3_root = (const float*)d_in[11];
  const float* pool_w  = (const float*)d_in[12];
  const float* Wl1     = (const float*)d_in[13];
  const float* bl1     = (const float*)d_in[14];
  const float* Wl2     = (const float*)d_in[15];
  const float* bl2     = (const float*)d_in[16];
  const float* Wl3     = (const float*)d_in[17];
  const float* bl3     = (const float*)d_in[18];
  float* out = (float*)d_out;

  // workspace layout
  char* w = (char*)d_ws;
  size_t off = 0;
  auto alloc = [&](size_t bytes) -> char* {
    off = (off + 255) & ~(size_t)255;
    char* p = w + off;
    off += bytes;
    return p;
  };
  int* deg1     = (int*)alloc((NB + 4096) * 4);   // +pad for exscan int4 tiles
  int* rs1      = (int*)alloc((NB + 1) * 4);
  int* cursor1  = (int*)alloc(NB * 4);
  int* csr1     = (int*)alloc((size_t)EE * 4);
  int* new_id   = (int*)alloc(NB * 4);
  int* perm     = (int*)alloc(N1 * 4);
  _Float16* wh1 = (_Float16*)alloc(128 * 128 * 2);
  _Float16* wl1 = (_Float16*)alloc(128 * 128 * 2);
  _Float16* wh2 = (_Float16*)alloc(128 * 256 * 2);
  _Float16* wl2 = (_Float16*)alloc(128 * 256 * 2);
  _Float16* wh3 = (_Float16*)alloc(128 * 256 * 2);
  _Float16* wl3 = (_Float16*)alloc(128 * 256 * 2);
  float* bufA   = (float*)alloc((size_t)NB * HH * 4);  // h1, then h3 (padded rows)
  float* bufB   = (float*)alloc((size_t)NB * HH * 4);  // h2, then h4 (padded rows)
  float* score  = (float*)alloc(NB * 4);
  float* pm1    = (float*)alloc(BG * 64 * HH * 4);
  float* ps1    = (float*)alloc(BG * 64 * HH * 4);
  float* pm2    = (float*)alloc(BG * 26 * HH * 4);
  float* ps2    = (float*)alloc(BG * 26 * HH * 4);
  float* pm3    = (float*)alloc(BG * 52 * HH * 4);
  float* ps3    = (float*)alloc(BG * 52 * HH * 4);
  if (off > ws_size) return;  // workspace too small: fail visibly

  const int TB = 256;
  const int egrid = (EE + TB - 1) / TB;

  hipMemsetAsync(deg1, 0, (NB + 4096) * 4, stream);
  hipMemsetAsync(new_id, 0xFF, NB * 4, stream);  // -1

  prep_weights_f16<<<(128 * 128 + 2 * 128 * 256 + TB - 1) / TB, TB, 0, stream>>>(
      W1_rel, W1_root, W2_rel, W2_root, W3_rel, W3_root, wh1, wl1, wh2, wl2, wh3, wl3);

  // CSR1 (src -> dst)
  deg_kernel<<<egrid, TB, 0, stream>>>(dst, deg1, EE);
  exscan_kernel<<<1, 1024, 0, stream>>>(deg1, rs1, cursor1, NB);
  scatter_kernel<<<egrid, TB, 0, stream>>>(src, dst, cursor1, csr1, EE);

  // conv1: gather + GEMM + x1 pool fused (32-row tiles)
  conv_mfma<64, 64, 1, 0, 0><<<NB / 32, 512, 0, stream>>>(
      x, x, rs1, csr1, nullptr, nullptr, wh1, wl1, b1, bufA, NB, NB / 32, pm1, ps1,
      nullptr, nullptr);

  // conv2: gather + GEMM + score fused
  conv_mfma<128, 128, 0, 1, 0><<<NB / 32, 512, 0, stream>>>(
      bufA, bufA, rs1, csr1, nullptr, nullptr, wh2, wl2, b2, bufB, NB, NB / 32,
      nullptr, nullptr, pool_w, score);

  // topk (radix-select); h3 gather (f4, padded ids); x2 pool partials
  topk_kernel<<<BG, 256, 0, stream>>>(score, perm);
  h3_kernel<<<(N1 * 32 + TB - 1) / TB, TB, 0, stream>>>((const float4*)bufB, perm, score,
                                                        (float4*)bufA, new_id);
  pool2_kernel<<<BG * 26, 128, 0, stream>>>(bufA, pm2, ps2);

  // conv3: gather via CSR1 + new_id remap (no CSR2 build) + GEMM + x3 pool fused
  conv_mfma<128, 128, 2, 0, 1><<<N1P / 32, 512, 0, stream>>>(
      bufA, bufA, rs1, csr1, perm, new_id, wh3, wl3, b3, bufB, N1P, N1P / 32, pm3, ps3,
      nullptr, nullptr);

  // pool finals + MLP head + log_softmax (fused)
  mlp_kernel<<<BG, 128, 0, stream>>>(pm1, ps1, pm2, ps2, pm3, ps3,
                                     Wl1, bl1, Wl2, bl2, Wl3, bl3, out);
}

// Round 15
// 227.525 us; speedup vs baseline: 1.1225x; 1.1225x over previous
//
#include <hip/hip_runtime.h>
#include <hip/hip_bf16.h>
#include <math.h>

#define NB 32768      // total nodes (B*N)
#define NN 2048       // nodes per graph
#define BG 16         // graphs
#define KK 1639       // kept per graph (0.8*2048 ceil)
#define KKP 1664      // kept rows padded to 64*26 = 13*128
#define N1 (BG*KK)    // 26224 real kept nodes
#define N1P (BG*KKP)  // 26624 padded kept rows
#define EE 524288     // total edges
#define HH 128        // hidden
#define FIN 64        // input features

using half8 = __attribute__((ext_vector_type(8))) _Float16;
using half4 = __attribute__((ext_vector_type(4))) _Float16;
using f32x4 = __attribute__((ext_vector_type(4))) float;

__device__ __forceinline__ void acc4(f32x4& a, const float4& v) {
  a[0] += v.x; a[1] += v.y; a[2] += v.z; a[3] += v.w;
}

// ---------------- CSR build (layer-1 graph only) ----------------
__global__ void deg_kernel(const int* __restrict__ dst, int* deg, int n) {
  int e = blockIdx.x * blockDim.x + threadIdx.x;
  if (e < n) atomicAdd(&deg[dst[e]], 1);
}

// single-block coalesced exclusive scan (int4 tiles of 4096); deg must be padded.
__global__ void exscan_kernel(const int* __restrict__ deg, int* rs, int* cursor, int n) {
  __shared__ int wsum[16];
  __shared__ int carry;
  int t = threadIdx.x;  // 1024
  int lane = t & 63, wid = t >> 6;
  if (t == 0) carry = 0;
  __syncthreads();
  int ntiles = (n + 4095) >> 12;
  for (int tile = 0; tile < ntiles; ++tile) {
    int idx = (tile << 12) + t * 4;
    int4 v4 = *(const int4*)(deg + idx);
    int v0 = (idx + 0 < n) ? v4.x : 0;
    int v1 = (idx + 1 < n) ? v4.y : 0;
    int v2 = (idx + 2 < n) ? v4.z : 0;
    int v3 = (idx + 3 < n) ? v4.w : 0;
    int s = v0 + v1 + v2 + v3;
    int pre = s;
#pragma unroll
    for (int off = 1; off < 64; off <<= 1) {
      int u = __shfl_up(pre, off, 64);
      if (lane >= off) pre += u;
    }
    if (lane == 63) wsum[wid] = pre;
    __syncthreads();
    int wbase = 0;
#pragma unroll
    for (int ww = 0; ww < 16; ++ww)
      if (ww < wid) wbase += wsum[ww];
    int ex = carry + wbase + (pre - s);
    int4 e4 = make_int4(ex, ex + v0, ex + v0 + v1, ex + v0 + v1 + v2);
    if (idx + 3 < n) {
      *(int4*)(rs + idx) = e4;
      *(int4*)(cursor + idx) = e4;
    } else {
      if (idx + 0 < n) { rs[idx + 0] = e4.x; cursor[idx + 0] = e4.x; }
      if (idx + 1 < n) { rs[idx + 1] = e4.y; cursor[idx + 1] = e4.y; }
      if (idx + 2 < n) { rs[idx + 2] = e4.z; cursor[idx + 2] = e4.z; }
    }
    int tot = 0;
    if (t == 1023) tot = ex + s;
    __syncthreads();
    if (t == 1023) carry = tot;
    __syncthreads();
  }
  if (t == 0) rs[n] = carry;
}

__global__ void scatter_kernel(const int* __restrict__ src, const int* __restrict__ dst,
                               int* cursor, int* csr, int n) {
  int e = blockIdx.x * blockDim.x + threadIdx.x;
  if (e < n) {
    int d = dst[e];
    int p = atomicAdd(&cursor[d], 1);
    csr[p] = src[e];
  }
}

// ---------------- fused agg + conv GEMM (+optional pool / score epilogues) ----------------
// 64-ROW TILE (R13 geometry — best measured): 512 thr = 8 waves; tile = 64x128;
// wave = 64x16 (4 row frags). Phase 1a: wave-coalesced CSR gather (8 rows/wave,
// 8 edge-batches in flight). REMAP=1 (conv3): row -> perm -> CSR1; src kept iff
// new_id[src]>=0. Phase 1b: root staging. Phase 2: ds_read + MFMA, W dbuf from L2.
// POOL=1: x1 partials (32 slices of 64). POOL=2: x3 partials (26 slices, >=KK masked).
// SCORE=1: per-row tanh(dot(h,w)/||w||).
template <int KD1, int KD2, int POOL, int SCORE, int REMAP>
__global__ __launch_bounds__(512, 4) void conv_mfma(
    const float* __restrict__ feat, const float* __restrict__ xr,
    const int* __restrict__ rs, const int* __restrict__ csr,
    const int* __restrict__ perm, const int* __restrict__ new_id,
    const _Float16* __restrict__ Wh, const _Float16* __restrict__ Wl,
    const float* __restrict__ bias, float* __restrict__ out, int M, int nwg,
    float* __restrict__ pmax, float* __restrict__ psum,
    const float* __restrict__ pw, float* __restrict__ score) {
  constexpr int KTOT = KD1 + KD2;
  constexpr int NSTEP = KTOT / 32;
  __shared__ _Float16 ah_lds[64 * KTOT];
  __shared__ _Float16 al_lds[64 * KTOT];
  __shared__ float sdot[64][8];
  __shared__ float swsq[8];

  int tid = threadIdx.x;
  int lane = tid & 63, wid = tid >> 6;
  // bijective XCD-chunk swizzle (m204)
  int bq = nwg >> 3, br = nwg & 7, bx = blockIdx.x & 7, bi = blockIdx.x >> 3;
  int swz = (bx < br ? bx * (bq + 1) : br * (bq + 1) + (bx - br) * bq) + bi;
  int row0 = swz * 64;
  int ch0 = wid * 16;
  int col = lane & 15;
  int kseg = (lane >> 4) * 8;

  // ---- Phase 1a: wave-coalesced CSR gather (k in [0, KD1)), 8-deep MLP ----
  {
    constexpr int CH = KD1 / 4;     // f4 chunks per row (16 or 32)
    constexpr int EPW = 64 / CH;    // edges per wave step (4 or 2)
    int sub = lane / CH;
    int ch = lane % CH;
    const float4* feat4 = (const float4*)feat;
#pragma unroll
    for (int rr = 0; rr < 8; ++rr) {
      int gr = wid * 8 + rr;
      int grow = row0 + gr;
      int e0 = 0, e1 = 0;
      if (REMAP) {
        int g = grow / KKP, j = grow - g * KKP;
        if (j < KK) {
          int oldrow = perm[g * KK + j];
          e0 = rs[oldrow];
          e1 = rs[oldrow + 1];
        }
      } else {
        if (grow >= M) grow = M - 1;
        e0 = rs[grow];
        e1 = rs[grow + 1];
      }
      f32x4 a0 = {0.f, 0.f, 0.f, 0.f}, a1 = a0, a2 = a0, a3 = a0;
      int e = e0 + sub;
      for (; e + 7 * EPW < e1; e += 8 * EPW) {
        int c[8];
#pragma unroll
        for (int u = 0; u < 8; ++u) c[u] = csr[e + u * EPW];
        if (REMAP) {
#pragma unroll
          for (int u = 0; u < 8; ++u) c[u] = new_id[c[u]];
        }
        float4 v[8];
#pragma unroll
        for (int u = 0; u < 8; ++u) {
          int ci = (REMAP && c[u] < 0) ? 0 : c[u];
          v[u] = feat4[(size_t)ci * CH + ch];
        }
        if (REMAP) {
#pragma unroll
          for (int u = 0; u < 8; ++u)
            if (c[u] < 0) v[u] = make_float4(0.f, 0.f, 0.f, 0.f);
        }
        acc4(a0, v[0]); acc4(a1, v[1]); acc4(a2, v[2]); acc4(a3, v[3]);
        acc4(a0, v[4]); acc4(a1, v[5]); acc4(a2, v[6]); acc4(a3, v[7]);
      }
      for (; e + 3 * EPW < e1; e += 4 * EPW) {
        int c[4];
#pragma unroll
        for (int u = 0; u < 4; ++u) c[u] = csr[e + u * EPW];
        if (REMAP) {
#pragma unroll
          for (int u = 0; u < 4; ++u) c[u] = new_id[c[u]];
        }
        float4 v[4];
#pragma unroll
        for (int u = 0; u < 4; ++u) {
          int ci = (REMAP && c[u] < 0) ? 0 : c[u];
          v[u] = feat4[(size_t)ci * CH + ch];
        }
        if (REMAP) {
#pragma unroll
          for (int u = 0; u < 4; ++u)
            if (c[u] < 0) v[u] = make_float4(0.f, 0.f, 0.f, 0.f);
        }
        acc4(a0, v[0]); acc4(a1, v[1]); acc4(a2, v[2]); acc4(a3, v[3]);
      }
      for (; e < e1; e += EPW) {
        int c = csr[e];
        if (REMAP) {
          c = new_id[c];
          if (c < 0) continue;
        }
        float4 v = feat4[(size_t)c * CH + ch];
        acc4(a0, v);
      }
      f32x4 s = (a0 + a1) + (a2 + a3);
      if (EPW == 4) {
#pragma unroll
        for (int j = 0; j < 4; ++j) s[j] += __shfl_xor(s[j], 16, 64);
      }
#pragma unroll
      for (int j = 0; j < 4; ++j) s[j] += __shfl_xor(s[j], 32, 64);
      if (sub == 0) {
        half4 hi, lo;
#pragma unroll
        for (int j = 0; j < 4; ++j) {
          _Float16 h = (_Float16)s[j];
          hi[j] = h;
          lo[j] = (_Float16)(s[j] - (float)h);
        }
        int byte = ((gr * KTOT + ch * 4) * 2) ^ ((gr & 7) << 4);
        *(half4*)((char*)ah_lds + byte) = hi;
        *(half4*)((char*)al_lds + byte) = lo;
      }
    }
  }

  // ---- Phase 1b: root staging (k in [KD1, KTOT)) ----
  for (int idx = tid; idx < 64 * KD2 / 8; idx += 512) {
    int row = idx / (KD2 / 8);
    int kc = (idx % (KD2 / 8)) * 8;
    int grow = row0 + row;
    if (grow >= M) grow = M - 1;
    const float* sp = xr + (size_t)grow * KD2 + kc;
    float4 a0 = *(const float4*)sp;
    float4 a1 = *(const float4*)(sp + 4);
    float av[8] = {a0.x, a0.y, a0.z, a0.w, a1.x, a1.y, a1.z, a1.w};
    half8 vh, vl;
#pragma unroll
    for (int j = 0; j < 8; ++j) {
      _Float16 h = (_Float16)av[j];
      vh[j] = h;
      vl[j] = (_Float16)(av[j] - (float)h);
    }
    int byte = ((row * KTOT + KD1 + kc) * 2) ^ ((row & 7) << 4);
    *(half8*)((char*)ah_lds + byte) = vh;
    *(half8*)((char*)al_lds + byte) = vl;
  }

  // issue first W step before the barrier (latency hides under barrier wait)
  size_t wbase = (size_t)(ch0 + col) * KTOT + kseg;
  half8 whc = *(const half8*)(Wh + wbase);
  half8 wlc = *(const half8*)(Wl + wbase);
  __syncthreads();

  // ---- Phase 2: k-loop; W double-buffered from L2, A from LDS ----
  f32x4 acc[4];
#pragma unroll
  for (int rf = 0; rf < 4; ++rf) acc[rf] = (f32x4){0.f, 0.f, 0.f, 0.f};
  int r = lane & 15;
#pragma unroll
  for (int s = 0; s < NSTEP; ++s) {
    half8 whn, wln;
    if (s + 1 < NSTEP) {  // compile-time after unroll
      whn = *(const half8*)(Wh + wbase + (s + 1) * 32);
      wln = *(const half8*)(Wl + wbase + (s + 1) * 32);
    }
#pragma unroll
    for (int rf = 0; rf < 4; ++rf) {
      int row = rf * 16 + r;
      int byte = ((row * KTOT + s * 32 + kseg) * 2) ^ ((row & 7) << 4);
      half8 a_h = *(const half8*)((const char*)ah_lds + byte);
      half8 a_l = *(const half8*)((const char*)al_lds + byte);
      acc[rf] = __builtin_amdgcn_mfma_f32_16x16x32_f16(a_l, whc, acc[rf], 0, 0, 0);
      acc[rf] = __builtin_amdgcn_mfma_f32_16x16x32_f16(a_h, wlc, acc[rf], 0, 0, 0);
      acc[rf] = __builtin_amdgcn_mfma_f32_16x16x32_f16(a_h, whc, acc[rf], 0, 0, 0);
    }
    if (s + 1 < NSTEP) { whc = whn; wlc = wln; }
  }

  // ---- epilogue: bias + relu (+ pool partials / score) ----
  float bv = bias[ch0 + col];
  float cmax = -3.402823466e38f, csum = 0.f;
  float wcol = SCORE ? pw[ch0 + col] : 0.f;
  float pd[4][4];
  int g = 0, rowbase = 0;
  if (POOL == 2) { g = row0 / KKP; rowbase = row0 - g * KKP; }
#pragma unroll
  for (int rf = 0; rf < 4; ++rf) {
    int orow0 = row0 + rf * 16 + (lane >> 4) * 4;
#pragma unroll
    for (int rr = 0; rr < 4; ++rr) {
      int orow = orow0 + rr;
      float v = fmaxf(acc[rf][rr] + bv, 0.f);
      if (orow < M) out[(size_t)orow * HH + ch0 + col] = v;
      if (POOL == 1) { cmax = fmaxf(cmax, v); csum += v; }
      if (POOL == 2) {
        int local = rowbase + rf * 16 + (lane >> 4) * 4 + rr;
        if (local < KK) { cmax = fmaxf(cmax, v); csum += v; }
      }
      if (SCORE) pd[rf][rr] = v * wcol;
    }
  }
  if (POOL) {
    cmax = fmaxf(cmax, __shfl_xor(cmax, 16, 64)); csum += __shfl_xor(csum, 16, 64);
    cmax = fmaxf(cmax, __shfl_xor(cmax, 32, 64)); csum += __shfl_xor(csum, 32, 64);
    if ((lane >> 4) == 0) {
      if (POOL == 1) {
        int gg = row0 >> 11, sb = (row0 & 2047) >> 6;  // 32 slices of 64 rows
        pmax[(gg * 32 + sb) * HH + ch0 + col] = cmax;
        psum[(gg * 32 + sb) * HH + ch0 + col] = csum;
      } else {
        int sb = rowbase >> 6;                          // 26 slices of 64 rows
        pmax[(g * 26 + sb) * HH + ch0 + col] = cmax;
        psum[(g * 26 + sb) * HH + ch0 + col] = csum;
      }
    }
  }
  if (SCORE) {
#pragma unroll
    for (int rf = 0; rf < 4; ++rf)
#pragma unroll
      for (int rr = 0; rr < 4; ++rr) {
        float d = pd[rf][rr];
        d += __shfl_xor(d, 1, 64); d += __shfl_xor(d, 2, 64);
        d += __shfl_xor(d, 4, 64); d += __shfl_xor(d, 8, 64);
        if (col == 0) sdot[rf * 16 + (lane >> 4) * 4 + rr][wid] = d;
      }
    float wsq = wcol * wcol;
    wsq += __shfl_xor(wsq, 1, 64); wsq += __shfl_xor(wsq, 2, 64);
    wsq += __shfl_xor(wsq, 4, 64); wsq += __shfl_xor(wsq, 8, 64);
    if (lane == 0) swsq[wid] = wsq;
    __syncthreads();
    if (tid < 64) {
      float d = 0.f, q = 0.f;
#pragma unroll
      for (int wv = 0; wv < 8; ++wv) { d += sdot[tid][wv]; q += swsq[wv]; }
      score[row0 + tid] = tanhf(d * rsqrtf(q));
    }
  }
}

// ---------------- weight prep: split Wcat[o][k] into f16 hi + lo planes ----------------
__global__ void prep_weights_f16(const float* __restrict__ W1_rel, const float* __restrict__ W1_root,
                                 const float* __restrict__ W2_rel, const float* __restrict__ W2_root,
                                 const float* __restrict__ W3_rel, const float* __restrict__ W3_root,
                                 _Float16* wh1, _Float16* wl1, _Float16* wh2, _Float16* wl2,
                                 _Float16* wh3, _Float16* wl3) {
  int idx = blockIdx.x * blockDim.x + threadIdx.x;
  float v;
  _Float16* ph;
  _Float16* pl;
  int j;
  if (idx < 128 * 128) {
    j = idx;
    int o = j >> 7, k = j & 127;
    v = (k < 64) ? W1_rel[o * 64 + k] : W1_root[o * 64 + (k - 64)];
    ph = wh1; pl = wl1;
  } else if (idx < 128 * 128 + 128 * 256) {
    j = idx - 128 * 128;
    int o = j >> 8, k = j & 255;
    v = (k < 128) ? W2_rel[o * 128 + k] : W2_root[o * 128 + (k - 128)];
    ph = wh2; pl = wl2;
  } else if (idx < 128 * 128 + 2 * 128 * 256) {
    j = idx - 128 * 128 - 128 * 256;
    int o = j >> 8, k = j & 255;
    v = (k < 128) ? W3_rel[o * 128 + k] : W3_root[o * 128 + (k - 128)];
    ph = wh3; pl = wl3;
  } else {
    return;
  }
  _Float16 h = (_Float16)v;
  ph[j] = h;
  pl[j] = (_Float16)(v - (float)h);
}

// ---------------- topk via radix-select (keys distinct -> exact set) ----------------
// Output order is arbitrary (downstream is order-invariant); 256 thr/block, 1 block/graph.
__global__ void topk_kernel(const float* __restrict__ score, int* perm) {
  __shared__ unsigned long long keys[NN];
  __shared__ int hist[256];
  __shared__ unsigned long long sP;
  __shared__ int srem;
  __shared__ int scnt;
  int b = blockIdx.x, t = threadIdx.x;  // 256 threads
  for (int i = t; i < NN; i += 256) {
    float s = score[b * NN + i];
    unsigned u = __float_as_uint(s);
    u = (u & 0x80000000u) ? ~u : (u | 0x80000000u);
    keys[i] = ((unsigned long long)u << 32) | (unsigned)(NN - 1 - i);
  }
  if (t == 0) { sP = 0ULL; srem = KK; scnt = 0; }
  __syncthreads();
  for (int pass = 0; pass < 8; ++pass) {
    int shift = 56 - 8 * pass;
    for (int i = t; i < 256; i += 256) hist[i] = 0;
    __syncthreads();
    unsigned long long P = sP;
    unsigned long long hm = (pass == 0) ? 0ULL : (~0ULL) << (shift + 8);
    for (int i = t; i < NN; i += 256) {
      unsigned long long k = keys[i];
      if (((k ^ P) & hm) == 0) atomicAdd(&hist[(int)((k >> shift) & 255)], 1);
    }
    __syncthreads();
    if (t < 64) {
      int l = t;
      int c[4], part = 0;
#pragma unroll
      for (int q = 0; q < 4; ++q) { c[q] = hist[255 - (l * 4 + q)]; part += c[q]; }
      int pre = part;
#pragma unroll
      for (int off = 1; off < 64; off <<= 1) {
        int u2 = __shfl_up(pre, off, 64);
        if (l >= off) pre += u2;
      }
      int excl = pre - part;
      int rem = srem;
      if (excl < rem && rem <= excl + part) {
        int run = excl;
#pragma unroll
        for (int q = 0; q < 4; ++q) {
          if (run + c[q] >= rem) {
            srem = rem - run;
            sP = sP | ((unsigned long long)(255 - (l * 4 + q)) << shift);
            break;
          }
          run += c[q];
        }
      }
    }
    __syncthreads();
  }
  unsigned long long T = sP;  // key of the K-th largest element (exact)
  for (int i = t; i < NN; i += 256) {
    if (keys[i] >= T) {
      int pos = atomicAdd(&scnt, 1);
      perm[b * KK + pos] = b * NN + (NN - 1 - (int)(keys[i] & 0xffffffffULL));
    }
  }
}

// gather kept rows (f4), scale by score, write new_id (padded id space)
__global__ void h3_kernel(const float4* __restrict__ h2, const int* __restrict__ perm,
                          const float* __restrict__ score, float4* __restrict__ h3,
                          int* __restrict__ new_id) {
  int idx = blockIdx.x * blockDim.x + threadIdx.x;  // over N1*32 float4s
  if (idx < N1 * 32) {
    int g = idx >> 5, c = idx & 31;
    int b = g / KK, j = g - b * KK;
    int p = perm[g];
    if (c == 0) new_id[p] = b * KKP + j;
    float s = score[p];
    float4 v = h2[(size_t)p * 32 + c];
    v.x *= s; v.y *= s; v.z *= s; v.w *= s;
    h3[(size_t)(b * KKP + j) * 32 + c] = v;
  }
}

// x2 pool partials over padded h3 layout: BG x 26 slices of 64 rows (<KK masked)
__global__ void pool2_kernel(const float* __restrict__ h, float* pmax, float* psum) {
  int b = blockIdx.x / 26, s = blockIdx.x % 26;
  int f = threadIdx.x;
  int r0 = s * 64, r1 = min(KK, r0 + 64);
  float m = -3.402823466e38f, sum = 0.f;
  for (int r = r0; r < r1; ++r) {
    float v = h[(size_t)(b * KKP + r) * HH + f];
    m = fmaxf(m, v);
    sum += v;
  }
  pmax[(b * 26 + s) * HH + f] = m;
  psum[(b * 26 + s) * HH + f] = sum;
}

// ---------------- final: pool-final x3 + MLP + log_softmax ----------------
__global__ void mlp_kernel(const float* __restrict__ pm1, const float* __restrict__ ps1,
                           const float* __restrict__ pm2, const float* __restrict__ ps2,
                           const float* __restrict__ pm3, const float* __restrict__ ps3,
                           const float* __restrict__ Wl1, const float* __restrict__ bl1,
                           const float* __restrict__ Wl2, const float* __restrict__ bl2,
                           const float* __restrict__ Wl3, const float* __restrict__ bl3,
                           float* out) {
  __shared__ float z[256], a1[128], a2[64], a3[10], red[2];
  int b = blockIdx.x, t = threadIdx.x;  // 128 threads
  float m1 = -3.402823466e38f, m2 = m1, m3 = m1;
  float s1 = 0.f, s2 = 0.f, s3 = 0.f;
  for (int s = 0; s < 32; ++s) {  // x1: 32 slices (conv1 fused pool)
    int o = (b * 32 + s) * 128 + t;
    m1 = fmaxf(m1, pm1[o]); s1 += ps1[o];
  }
  for (int s = 0; s < 26; ++s) {  // x2/x3: 26 slices
    int o = (b * 26 + s) * 128 + t;
    m2 = fmaxf(m2, pm2[o]); s2 += ps2[o];
    m3 = fmaxf(m3, pm3[o]); s3 += ps3[o];
  }
  z[t] = m1 + m2 + m3;
  z[128 + t] = s1 * (1.f / NN) + (s2 + s3) * (1.f / KK);
  __syncthreads();
  {
    float acc = bl1[t];
    for (int q = 0; q < 256; ++q) acc = fmaf(Wl1[t * 256 + q], z[q], acc);
    a1[t] = fmaxf(acc, 0.f);
  }
  __syncthreads();
  if (t < 64) {
    float acc = bl2[t];
    for (int q = 0; q < 128; ++q) acc = fmaf(Wl2[t * 128 + q], a1[q], acc);
    a2[t] = fmaxf(acc, 0.f);
  }
  __syncthreads();
  if (t < 10) {
    float acc = bl3[t];
    for (int q = 0; q < 64; ++q) acc = fmaf(Wl3[t * 64 + q], a2[q], acc);
    a3[t] = acc;
  }
  __syncthreads();
  if (t == 0) {
    float m = a3[0];
    for (int i = 1; i < 10; ++i) m = fmaxf(m, a3[i]);
    float s = 0.f;
    for (int i = 0; i < 10; ++i) s += expf(a3[i] - m);
    red[0] = m;
    red[1] = logf(s);
  }
  __syncthreads();
  if (t < 10) out[b * 10 + t] = a3[t] - red[0] - red[1];
}

extern "C" void kernel_launch(void* const* d_in, const int* in_sizes, int n_in,
                              void* d_out, int out_size, void* d_ws, size_t ws_size,
                              hipStream_t stream) {
  const float* x       = (const float*)d_in[0];
  const int*   src     = (const int*)d_in[1];
  const int*   dst     = (const int*)d_in[2];
  const float* W1_rel  = (const float*)d_in[3];
  const float* b1      = (const float*)d_in[4];
  const float* W1_root = (const float*)d_in[5];
  const float* W2_rel  = (const float*)d_in[6];
  const float* b2      = (const float*)d_in[7];
  const float* W2_root = (const float*)d_in[8];
  const float* W3_rel  = (const float*)d_in[9];
  const float* b3      = (const float*)d_in[10];
  const float* W3_root = (const float*)d_in[11];
  const float* pool_w  = (const float*)d_in[12];
  const float* Wl1     = (const float*)d_in[13];
  const float* bl1     = (const float*)d_in[14];
  const float* Wl2     = (const float*)d_in[15];
  const float* bl2     = (const float*)d_in[16];
  const float* Wl3     = (const float*)d_in[17];
  const float* bl3     = (const float*)d_in[18];
  float* out = (float*)d_out;

  // workspace layout
  char* w = (char*)d_ws;
  size_t off = 0;
  auto alloc = [&](size_t bytes) -> char* {
    off = (off + 255) & ~(size_t)255;
    char* p = w + off;
    off += bytes;
    return p;
  };
  int* deg1     = (int*)alloc((NB + 4096) * 4);   // +pad for exscan int4 tiles
  int* rs1      = (int*)alloc((NB + 1) * 4);
  int* cursor1  = (int*)alloc(NB * 4);
  int* csr1     = (int*)alloc((size_t)EE * 4);
  int* new_id   = (int*)alloc(NB * 4);
  int* perm     = (int*)alloc(N1 * 4);
  _Float16* wh1 = (_Float16*)alloc(128 * 128 * 2);
  _Float16* wl1 = (_Float16*)alloc(128 * 128 * 2);
  _Float16* wh2 = (_Float16*)alloc(128 * 256 * 2);
  _Float16* wl2 = (_Float16*)alloc(128 * 256 * 2);
  _Float16* wh3 = (_Float16*)alloc(128 * 256 * 2);
  _Float16* wl3 = (_Float16*)alloc(128 * 256 * 2);
  float* bufA   = (float*)alloc((size_t)NB * HH * 4);  // h1, then h3 (padded rows)
  float* bufB   = (float*)alloc((size_t)NB * HH * 4);  // h2, then h4 (padded rows)
  float* score  = (float*)alloc(NB * 4);
  float* pm1    = (float*)alloc(BG * 32 * HH * 4);
  float* ps1    = (float*)alloc(BG * 32 * HH * 4);
  float* pm2    = (float*)alloc(BG * 26 * HH * 4);
  float* ps2    = (float*)alloc(BG * 26 * HH * 4);
  float* pm3    = (float*)alloc(BG * 26 * HH * 4);
  float* ps3    = (float*)alloc(BG * 26 * HH * 4);
  if (off > ws_size) return;  // workspace too small: fail visibly

  const int TB = 256;
  const int egrid = (EE + TB - 1) / TB;

  hipMemsetAsync(deg1, 0, (NB + 4096) * 4, stream);
  hipMemsetAsync(new_id, 0xFF, NB * 4, stream);  // -1

  prep_weights_f16<<<(128 * 128 + 2 * 128 * 256 + TB - 1) / TB, TB, 0, stream>>>(
      W1_rel, W1_root, W2_rel, W2_root, W3_rel, W3_root, wh1, wl1, wh2, wl2, wh3, wl3);

  // CSR1 (src -> dst)
  deg_kernel<<<egrid, TB, 0, stream>>>(dst, deg1, EE);
  exscan_kernel<<<1, 1024, 0, stream>>>(deg1, rs1, cursor1, NB);
  scatter_kernel<<<egrid, TB, 0, stream>>>(src, dst, cursor1, csr1, EE);

  // conv1: gather + GEMM + x1 pool fused (64-row tiles)
  conv_mfma<64, 64, 1, 0, 0><<<NB / 64, 512, 0, stream>>>(
      x, x, rs1, csr1, nullptr, nullptr, wh1, wl1, b1, bufA, NB, NB / 64, pm1, ps1,
      nullptr, nullptr);

  // conv2: gather + GEMM + score fused
  conv_mfma<128, 128, 0, 1, 0><<<NB / 64, 512, 0, stream>>>(
      bufA, bufA, rs1, csr1, nullptr, nullptr, wh2, wl2, b2, bufB, NB, NB / 64,
      nullptr, nullptr, pool_w, score);

  // topk (radix-select); h3 gather (f4, padded ids); x2 pool partials
  topk_kernel<<<BG, 256, 0, stream>>>(score, perm);
  h3_kernel<<<(N1 * 32 + TB - 1) / TB, TB, 0, stream>>>((const float4*)bufB, perm, score,
                                                        (float4*)bufA, new_id);
  pool2_kernel<<<BG * 26, 128, 0, stream>>>(bufA, pm2, ps2);

  // conv3: gather via CSR1 + new_id remap (no CSR2 build) + GEMM + x3 pool fused
  conv_mfma<128, 128, 2, 0, 1><<<N1P / 64, 512, 0, stream>>>(
      bufA, bufA, rs1, csr1, perm, new_id, wh3, wl3, b3, bufB, N1P, N1P / 64, pm3, ps3,
      nullptr, nullptr);

  // pool finals + MLP head + log_softmax (fused)
  mlp_kernel<<<BG, 128, 0, stream>>>(pm1, ps1, pm2, ps2, pm3, ps3,
                                     Wl1, bl1, Wl2, bl2, Wl3, bl3, out);
}

// Round 16
// 220.545 us; speedup vs baseline: 1.1581x; 1.0317x over previous
//
#include <hip/hip_runtime.h>
#include <hip/hip_bf16.h>
#include <math.h>

#define NB 32768      // total nodes (B*N)
#define NN 2048       // nodes per graph
#define BG 16         // graphs
#define KK 1639       // kept per graph (0.8*2048 ceil)
#define KKP 1664      // kept rows padded to 64*26 = 13*128
#define N1 (BG*KK)    // 26224 real kept nodes
#define N1P (BG*KKP)  // 26624 padded kept rows
#define EE 524288     // total edges
#define HH 128        // hidden
#define FIN 64        // input features

using half8 = __attribute__((ext_vector_type(8))) _Float16;
using half4 = __attribute__((ext_vector_type(4))) _Float16;
using f32x4 = __attribute__((ext_vector_type(4))) float;

__device__ __forceinline__ void acc4(f32x4& a, const float4& v) {
  a[0] += v.x; a[1] += v.y; a[2] += v.z; a[3] += v.w;
}

// ---------------- CSR build (layer-1 graph only) ----------------
__global__ void deg_kernel(const int* __restrict__ dst, int* deg, int n) {
  int e = blockIdx.x * blockDim.x + threadIdx.x;
  if (e < n) atomicAdd(&deg[dst[e]], 1);
}

// single-block coalesced exclusive scan (int4 tiles of 4096); deg must be padded.
__global__ void exscan_kernel(const int* __restrict__ deg, int* rs, int* cursor, int n) {
  __shared__ int wsum[16];
  __shared__ int carry;
  int t = threadIdx.x;  // 1024
  int lane = t & 63, wid = t >> 6;
  if (t == 0) carry = 0;
  __syncthreads();
  int ntiles = (n + 4095) >> 12;
  for (int tile = 0; tile < ntiles; ++tile) {
    int idx = (tile << 12) + t * 4;
    int4 v4 = *(const int4*)(deg + idx);
    int v0 = (idx + 0 < n) ? v4.x : 0;
    int v1 = (idx + 1 < n) ? v4.y : 0;
    int v2 = (idx + 2 < n) ? v4.z : 0;
    int v3 = (idx + 3 < n) ? v4.w : 0;
    int s = v0 + v1 + v2 + v3;
    int pre = s;
#pragma unroll
    for (int off = 1; off < 64; off <<= 1) {
      int u = __shfl_up(pre, off, 64);
      if (lane >= off) pre += u;
    }
    if (lane == 63) wsum[wid] = pre;
    __syncthreads();
    int wbase = 0;
#pragma unroll
    for (int ww = 0; ww < 16; ++ww)
      if (ww < wid) wbase += wsum[ww];
    int ex = carry + wbase + (pre - s);
    int4 e4 = make_int4(ex, ex + v0, ex + v0 + v1, ex + v0 + v1 + v2);
    if (idx + 3 < n) {
      *(int4*)(rs + idx) = e4;
      *(int4*)(cursor + idx) = e4;
    } else {
      if (idx + 0 < n) { rs[idx + 0] = e4.x; cursor[idx + 0] = e4.x; }
      if (idx + 1 < n) { rs[idx + 1] = e4.y; cursor[idx + 1] = e4.y; }
      if (idx + 2 < n) { rs[idx + 2] = e4.z; cursor[idx + 2] = e4.z; }
    }
    int tot = 0;
    if (t == 1023) tot = ex + s;
    __syncthreads();
    if (t == 1023) carry = tot;
    __syncthreads();
  }
  if (t == 0) rs[n] = carry;
}

__global__ void scatter_kernel(const int* __restrict__ src, const int* __restrict__ dst,
                               int* cursor, int* csr, int n) {
  int e = blockIdx.x * blockDim.x + threadIdx.x;
  if (e < n) {
    int d = dst[e];
    int p = atomicAdd(&cursor[d], 1);
    csr[p] = src[e];
  }
}

// csr3[e] = new_id[csr1[e]]  (pre-resolves conv3's dependent hop)
__global__ void remap_kernel(const int* __restrict__ csr1, const int* __restrict__ new_id,
                             int* __restrict__ csr3, int n) {
  int e = blockIdx.x * blockDim.x + threadIdx.x;
  if (e < n) csr3[e] = new_id[csr1[e]];
}

// ---------------- fused agg + conv GEMM (+optional pool / score epilogues) ----------------
// 64-ROW TILE: 512 thr = 8 waves; tile = 64x128; wave = 64x16 (4 row frags).
// Phase 1a: wave-coalesced CSR gather (8 rows/wave, 8 edge-batches in flight).
//   REMAP=0: row ranges from rs[]. REMAP=2 (conv3): row ranges from rows3/rowe3
//   (pre-resolved), csr entries pre-remapped (csr3, -1 = dropped src).
// Phase 1b: root staging. Phase 2: ds_read + MFMA, W dbuf from L2.
// POOL=1: x1 partials (32 slices of 64). POOL=2: x3 partials (26 slices, >=KK masked).
// SCORE=1: per-row tanh(dot(h,w)/||w||).
template <int KD1, int KD2, int POOL, int SCORE, int REMAP>
__global__ __launch_bounds__(512, 4) void conv_mfma(
    const float* __restrict__ feat, const float* __restrict__ xr,
    const int* __restrict__ rs, const int* __restrict__ csr,
    const int* __restrict__ rows3, const int* __restrict__ rowe3,
    const _Float16* __restrict__ Wh, const _Float16* __restrict__ Wl,
    const float* __restrict__ bias, float* __restrict__ out, int M, int nwg,
    float* __restrict__ pmax, float* __restrict__ psum,
    const float* __restrict__ pw, float* __restrict__ score) {
  constexpr int KTOT = KD1 + KD2;
  constexpr int NSTEP = KTOT / 32;
  __shared__ _Float16 ah_lds[64 * KTOT];
  __shared__ _Float16 al_lds[64 * KTOT];
  __shared__ float sdot[64][8];
  __shared__ float swsq[8];

  int tid = threadIdx.x;
  int lane = tid & 63, wid = tid >> 6;
  // bijective XCD-chunk swizzle (m204)
  int bq = nwg >> 3, br = nwg & 7, bx = blockIdx.x & 7, bi = blockIdx.x >> 3;
  int swz = (bx < br ? bx * (bq + 1) : br * (bq + 1) + (bx - br) * bq) + bi;
  int row0 = swz * 64;
  int ch0 = wid * 16;
  int col = lane & 15;
  int kseg = (lane >> 4) * 8;

  // ---- Phase 1a: wave-coalesced CSR gather (k in [0, KD1)), 8-deep MLP ----
  {
    constexpr int CH = KD1 / 4;     // f4 chunks per row (16 or 32)
    constexpr int EPW = 64 / CH;    // edges per wave step (4 or 2)
    int sub = lane / CH;
    int ch = lane % CH;
    const float4* feat4 = (const float4*)feat;
#pragma unroll
    for (int rr = 0; rr < 8; ++rr) {
      int gr = wid * 8 + rr;
      int grow = row0 + gr;
      int e0, e1;
      if (REMAP) {
        e0 = rows3[grow];
        e1 = rowe3[grow];
      } else {
        if (grow >= M) grow = M - 1;
        e0 = rs[grow];
        e1 = rs[grow + 1];
      }
      f32x4 a0 = {0.f, 0.f, 0.f, 0.f}, a1 = a0, a2 = a0, a3 = a0;
      int e = e0 + sub;
      for (; e + 7 * EPW < e1; e += 8 * EPW) {
        int c[8];
#pragma unroll
        for (int u = 0; u < 8; ++u) c[u] = csr[e + u * EPW];
        float4 v[8];
#pragma unroll
        for (int u = 0; u < 8; ++u) {
          int ci = (REMAP && c[u] < 0) ? 0 : c[u];
          v[u] = feat4[(size_t)ci * CH + ch];
        }
        if (REMAP) {
#pragma unroll
          for (int u = 0; u < 8; ++u)
            if (c[u] < 0) v[u] = make_float4(0.f, 0.f, 0.f, 0.f);
        }
        acc4(a0, v[0]); acc4(a1, v[1]); acc4(a2, v[2]); acc4(a3, v[3]);
        acc4(a0, v[4]); acc4(a1, v[5]); acc4(a2, v[6]); acc4(a3, v[7]);
      }
      for (; e + 3 * EPW < e1; e += 4 * EPW) {
        int c[4];
#pragma unroll
        for (int u = 0; u < 4; ++u) c[u] = csr[e + u * EPW];
        float4 v[4];
#pragma unroll
        for (int u = 0; u < 4; ++u) {
          int ci = (REMAP && c[u] < 0) ? 0 : c[u];
          v[u] = feat4[(size_t)ci * CH + ch];
        }
        if (REMAP) {
#pragma unroll
          for (int u = 0; u < 4; ++u)
            if (c[u] < 0) v[u] = make_float4(0.f, 0.f, 0.f, 0.f);
        }
        acc4(a0, v[0]); acc4(a1, v[1]); acc4(a2, v[2]); acc4(a3, v[3]);
      }
      for (; e < e1; e += EPW) {
        int c = csr[e];
        if (REMAP && c < 0) continue;
        float4 v = feat4[(size_t)c * CH + ch];
        acc4(a0, v);
      }
      f32x4 s = (a0 + a1) + (a2 + a3);
      if (EPW == 4) {
#pragma unroll
        for (int j = 0; j < 4; ++j) s[j] += __shfl_xor(s[j], 16, 64);
      }
#pragma unroll
      for (int j = 0; j < 4; ++j) s[j] += __shfl_xor(s[j], 32, 64);
      if (sub == 0) {
        half4 hi, lo;
#pragma unroll
        for (int j = 0; j < 4; ++j) {
          _Float16 h = (_Float16)s[j];
          hi[j] = h;
          lo[j] = (_Float16)(s[j] - (float)h);
        }
        int byte = ((gr * KTOT + ch * 4) * 2) ^ ((gr & 7) << 4);
        *(half4*)((char*)ah_lds + byte) = hi;
        *(half4*)((char*)al_lds + byte) = lo;
      }
    }
  }

  // ---- Phase 1b: root staging (k in [KD1, KTOT)) ----
  for (int idx = tid; idx < 64 * KD2 / 8; idx += 512) {
    int row = idx / (KD2 / 8);
    int kc = (idx % (KD2 / 8)) * 8;
    int grow = row0 + row;
    if (grow >= M) grow = M - 1;
    const float* sp = xr + (size_t)grow * KD2 + kc;
    float4 a0 = *(const float4*)sp;
    float4 a1 = *(const float4*)(sp + 4);
    float av[8] = {a0.x, a0.y, a0.z, a0.w, a1.x, a1.y, a1.z, a1.w};
    half8 vh, vl;
#pragma unroll
    for (int j = 0; j < 8; ++j) {
      _Float16 h = (_Float16)av[j];
      vh[j] = h;
      vl[j] = (_Float16)(av[j] - (float)h);
    }
    int byte = ((row * KTOT + KD1 + kc) * 2) ^ ((row & 7) << 4);
    *(half8*)((char*)ah_lds + byte) = vh;
    *(half8*)((char*)al_lds + byte) = vl;
  }

  // issue first W step before the barrier (latency hides under barrier wait)
  size_t wbase = (size_t)(ch0 + col) * KTOT + kseg;
  half8 whc = *(const half8*)(Wh + wbase);
  half8 wlc = *(const half8*)(Wl + wbase);
  __syncthreads();

  // ---- Phase 2: k-loop; W double-buffered from L2, A from LDS ----
  f32x4 acc[4];
#pragma unroll
  for (int rf = 0; rf < 4; ++rf) acc[rf] = (f32x4){0.f, 0.f, 0.f, 0.f};
  int r = lane & 15;
#pragma unroll
  for (int s = 0; s < NSTEP; ++s) {
    half8 whn, wln;
    if (s + 1 < NSTEP) {  // compile-time after unroll
      whn = *(const half8*)(Wh + wbase + (s + 1) * 32);
      wln = *(const half8*)(Wl + wbase + (s + 1) * 32);
    }
#pragma unroll
    for (int rf = 0; rf < 4; ++rf) {
      int row = rf * 16 + r;
      int byte = ((row * KTOT + s * 32 + kseg) * 2) ^ ((row & 7) << 4);
      half8 a_h = *(const half8*)((const char*)ah_lds + byte);
      half8 a_l = *(const half8*)((const char*)al_lds + byte);
      acc[rf] = __builtin_amdgcn_mfma_f32_16x16x32_f16(a_l, whc, acc[rf], 0, 0, 0);
      acc[rf] = __builtin_amdgcn_mfma_f32_16x16x32_f16(a_h, wlc, acc[rf], 0, 0, 0);
      acc[rf] = __builtin_amdgcn_mfma_f32_16x16x32_f16(a_h, whc, acc[rf], 0, 0, 0);
    }
    if (s + 1 < NSTEP) { whc = whn; wlc = wln; }
  }

  // ---- epilogue: bias + relu (+ pool partials / score) ----
  float bv = bias[ch0 + col];
  float cmax = -3.402823466e38f, csum = 0.f;
  float wcol = SCORE ? pw[ch0 + col] : 0.f;
  float pd[4][4];
  int g = 0, rowbase = 0;
  if (POOL == 2) { g = row0 / KKP; rowbase = row0 - g * KKP; }
#pragma unroll
  for (int rf = 0; rf < 4; ++rf) {
    int orow0 = row0 + rf * 16 + (lane >> 4) * 4;
#pragma unroll
    for (int rr = 0; rr < 4; ++rr) {
      int orow = orow0 + rr;
      float v = fmaxf(acc[rf][rr] + bv, 0.f);
      if (orow < M) out[(size_t)orow * HH + ch0 + col] = v;
      if (POOL == 1) { cmax = fmaxf(cmax, v); csum += v; }
      if (POOL == 2) {
        int local = rowbase + rf * 16 + (lane >> 4) * 4 + rr;
        if (local < KK) { cmax = fmaxf(cmax, v); csum += v; }
      }
      if (SCORE) pd[rf][rr] = v * wcol;
    }
  }
  if (POOL) {
    cmax = fmaxf(cmax, __shfl_xor(cmax, 16, 64)); csum += __shfl_xor(csum, 16, 64);
    cmax = fmaxf(cmax, __shfl_xor(cmax, 32, 64)); csum += __shfl_xor(csum, 32, 64);
    if ((lane >> 4) == 0) {
      if (POOL == 1) {
        int gg = row0 >> 11, sb = (row0 & 2047) >> 6;  // 32 slices of 64 rows
        pmax[(gg * 32 + sb) * HH + ch0 + col] = cmax;
        psum[(gg * 32 + sb) * HH + ch0 + col] = csum;
      } else {
        int sb = rowbase >> 6;                          // 26 slices of 64 rows
        pmax[(g * 26 + sb) * HH + ch0 + col] = cmax;
        psum[(g * 26 + sb) * HH + ch0 + col] = csum;
      }
    }
  }
  if (SCORE) {
#pragma unroll
    for (int rf = 0; rf < 4; ++rf)
#pragma unroll
      for (int rr = 0; rr < 4; ++rr) {
        float d = pd[rf][rr];
        d += __shfl_xor(d, 1, 64); d += __shfl_xor(d, 2, 64);
        d += __shfl_xor(d, 4, 64); d += __shfl_xor(d, 8, 64);
        if (col == 0) sdot[rf * 16 + (lane >> 4) * 4 + rr][wid] = d;
      }
    float wsq = wcol * wcol;
    wsq += __shfl_xor(wsq, 1, 64); wsq += __shfl_xor(wsq, 2, 64);
    wsq += __shfl_xor(wsq, 4, 64); wsq += __shfl_xor(wsq, 8, 64);
    if (lane == 0) swsq[wid] = wsq;
    __syncthreads();
    if (tid < 64) {
      float d = 0.f, q = 0.f;
#pragma unroll
      for (int wv = 0; wv < 8; ++wv) { d += sdot[tid][wv]; q += swsq[wv]; }
      score[row0 + tid] = tanhf(d * rsqrtf(q));
    }
  }
}

// ---------------- prep: weight f16 hi/lo split + all buffer inits (replaces memsets) ----
__global__ void prep_kernel(const float* __restrict__ W1_rel, const float* __restrict__ W1_root,
                            const float* __restrict__ W2_rel, const float* __restrict__ W2_root,
                            const float* __restrict__ W3_rel, const float* __restrict__ W3_root,
                            _Float16* wh1, _Float16* wl1, _Float16* wh2, _Float16* wl2,
                            _Float16* wh3, _Float16* wl3,
                            int* __restrict__ deg1, int* __restrict__ new_id,
                            int* __restrict__ rows3, int* __restrict__ rowe3) {
  int idx = blockIdx.x * blockDim.x + threadIdx.x;
  // inits (grid = 98304 threads covers all)
  if (idx < NB + 4096) deg1[idx] = 0;
  if (idx < NB) new_id[idx] = -1;
  if (idx < N1P) { rows3[idx] = 0; rowe3[idx] = 0; }
  // weight split
  float v;
  _Float16* ph;
  _Float16* pl;
  int j;
  if (idx < 128 * 128) {
    j = idx;
    int o = j >> 7, k = j & 127;
    v = (k < 64) ? W1_rel[o * 64 + k] : W1_root[o * 64 + (k - 64)];
    ph = wh1; pl = wl1;
  } else if (idx < 128 * 128 + 128 * 256) {
    j = idx - 128 * 128;
    int o = j >> 8, k = j & 255;
    v = (k < 128) ? W2_rel[o * 128 + k] : W2_root[o * 128 + (k - 128)];
    ph = wh2; pl = wl2;
  } else if (idx < 128 * 128 + 2 * 128 * 256) {
    j = idx - 128 * 128 - 128 * 256;
    int o = j >> 8, k = j & 255;
    v = (k < 128) ? W3_rel[o * 128 + k] : W3_root[o * 128 + (k - 128)];
    ph = wh3; pl = wl3;
  } else {
    return;
  }
  _Float16 h = (_Float16)v;
  ph[j] = h;
  pl[j] = (_Float16)(v - (float)h);
}

// ---------------- topk via radix-select (keys distinct -> exact set) ----------------
__global__ void topk_kernel(const float* __restrict__ score, int* perm) {
  __shared__ unsigned long long keys[NN];
  __shared__ int hist[256];
  __shared__ unsigned long long sP;
  __shared__ int srem;
  __shared__ int scnt;
  int b = blockIdx.x, t = threadIdx.x;  // 256 threads
  for (int i = t; i < NN; i += 256) {
    float s = score[b * NN + i];
    unsigned u = __float_as_uint(s);
    u = (u & 0x80000000u) ? ~u : (u | 0x80000000u);
    keys[i] = ((unsigned long long)u << 32) | (unsigned)(NN - 1 - i);
  }
  if (t == 0) { sP = 0ULL; srem = KK; scnt = 0; }
  __syncthreads();
  for (int pass = 0; pass < 8; ++pass) {
    int shift = 56 - 8 * pass;
    for (int i = t; i < 256; i += 256) hist[i] = 0;
    __syncthreads();
    unsigned long long P = sP;
    unsigned long long hm = (pass == 0) ? 0ULL : (~0ULL) << (shift + 8);
    for (int i = t; i < NN; i += 256) {
      unsigned long long k = keys[i];
      if (((k ^ P) & hm) == 0) atomicAdd(&hist[(int)((k >> shift) & 255)], 1);
    }
    __syncthreads();
    if (t < 64) {
      int l = t;
      int c[4], part = 0;
#pragma unroll
      for (int q = 0; q < 4; ++q) { c[q] = hist[255 - (l * 4 + q)]; part += c[q]; }
      int pre = part;
#pragma unroll
      for (int off = 1; off < 64; off <<= 1) {
        int u2 = __shfl_up(pre, off, 64);
        if (l >= off) pre += u2;
      }
      int excl = pre - part;
      int rem = srem;
      if (excl < rem && rem <= excl + part) {
        int run = excl;
#pragma unroll
        for (int q = 0; q < 4; ++q) {
          if (run + c[q] >= rem) {
            srem = rem - run;
            sP = sP | ((unsigned long long)(255 - (l * 4 + q)) << shift);
            break;
          }
          run += c[q];
        }
      }
    }
    __syncthreads();
  }
  unsigned long long T = sP;  // key of the K-th largest element (exact)
  for (int i = t; i < NN; i += 256) {
    if (keys[i] >= T) {
      int pos = atomicAdd(&scnt, 1);
      perm[b * KK + pos] = b * NN + (NN - 1 - (int)(keys[i] & 0xffffffffULL));
    }
  }
}

// gather kept rows (f4), scale by score, write new_id + pre-resolved row ranges
__global__ void h3_kernel(const float4* __restrict__ h2, const int* __restrict__ perm,
                          const float* __restrict__ score, const int* __restrict__ rs1,
                          float4* __restrict__ h3, int* __restrict__ new_id,
                          int* __restrict__ rows3, int* __restrict__ rowe3) {
  int idx = blockIdx.x * blockDim.x + threadIdx.x;  // over N1*32 float4s
  if (idx < N1 * 32) {
    int g = idx >> 5, c = idx & 31;
    int b = g / KK, j = g - b * KK;
    int p = perm[g];
    int pj = b * KKP + j;
    if (c == 0) {
      new_id[p] = pj;
      rows3[pj] = rs1[p];
      rowe3[pj] = rs1[p + 1];
    }
    float s = score[p];
    float4 v = h2[(size_t)p * 32 + c];
    v.x *= s; v.y *= s; v.z *= s; v.w *= s;
    h3[(size_t)pj * 32 + c] = v;
  }
}

// x2 pool partials over padded h3 layout: BG x 26 slices of 64 rows (<KK masked)
__global__ void pool2_kernel(const float* __restrict__ h, float* pmax, float* psum) {
  int b = blockIdx.x / 26, s = blockIdx.x % 26;
  int f = threadIdx.x;
  int r0 = s * 64, r1 = min(KK, r0 + 64);
  float m = -3.402823466e38f, sum = 0.f;
  for (int r = r0; r < r1; ++r) {
    float v = h[(size_t)(b * KKP + r) * HH + f];
    m = fmaxf(m, v);
    sum += v;
  }
  pmax[(b * 26 + s) * HH + f] = m;
  psum[(b * 26 + s) * HH + f] = sum;
}

// ---------------- final: pool-final x3 + MLP + log_softmax ----------------
__global__ void mlp_kernel(const float* __restrict__ pm1, const float* __restrict__ ps1,
                           const float* __restrict__ pm2, const float* __restrict__ ps2,
                           const float* __restrict__ pm3, const float* __restrict__ ps3,
                           const float* __restrict__ Wl1, const float* __restrict__ bl1,
                           const float* __restrict__ Wl2, const float* __restrict__ bl2,
                           const float* __restrict__ Wl3, const float* __restrict__ bl3,
                           float* out) {
  __shared__ float z[256], a1[128], a2[64], a3[10], red[2];
  int b = blockIdx.x, t = threadIdx.x;  // 128 threads
  float m1 = -3.402823466e38f, m2 = m1, m3 = m1;
  float s1 = 0.f, s2 = 0.f, s3 = 0.f;
  for (int s = 0; s < 32; ++s) {  // x1: 32 slices (conv1 fused pool)
    int o = (b * 32 + s) * 128 + t;
    m1 = fmaxf(m1, pm1[o]); s1 += ps1[o];
  }
  for (int s = 0; s < 26; ++s) {  // x2/x3: 26 slices
    int o = (b * 26 + s) * 128 + t;
    m2 = fmaxf(m2, pm2[o]); s2 += ps2[o];
    m3 = fmaxf(m3, pm3[o]); s3 += ps3[o];
  }
  z[t] = m1 + m2 + m3;
  z[128 + t] = s1 * (1.f / NN) + (s2 + s3) * (1.f / KK);
  __syncthreads();
  {
    float acc = bl1[t];
    for (int q = 0; q < 256; ++q) acc = fmaf(Wl1[t * 256 + q], z[q], acc);
    a1[t] = fmaxf(acc, 0.f);
  }
  __syncthreads();
  if (t < 64) {
    float acc = bl2[t];
    for (int q = 0; q < 128; ++q) acc = fmaf(Wl2[t * 128 + q], a1[q], acc);
    a2[t] = fmaxf(acc, 0.f);
  }
  __syncthreads();
  if (t < 10) {
    float acc = bl3[t];
    for (int q = 0; q < 64; ++q) acc = fmaf(Wl3[t * 64 + q], a2[q], acc);
    a3[t] = acc;
  }
  __syncthreads();
  if (t == 0) {
    float m = a3[0];
    for (int i = 1; i < 10; ++i) m = fmaxf(m, a3[i]);
    float s = 0.f;
    for (int i = 0; i < 10; ++i) s += expf(a3[i] - m);
    red[0] = m;
    red[1] = logf(s);
  }
  __syncthreads();
  if (t < 10) out[b * 10 + t] = a3[t] - red[0] - red[1];
}

extern "C" void kernel_launch(void* const* d_in, const int* in_sizes, int n_in,
                              void* d_out, int out_size, void* d_ws, size_t ws_size,
                              hipStream_t stream) {
  const float* x       = (const float*)d_in[0];
  const int*   src     = (const int*)d_in[1];
  const int*   dst     = (const int*)d_in[2];
  const float* W1_rel  = (const float*)d_in[3];
  const float* b1      = (const float*)d_in[4];
  const float* W1_root = (const float*)d_in[5];
  const float* W2_rel  = (const float*)d_in[6];
  const float* b2      = (const float*)d_in[7];
  const float* W2_root = (const float*)d_in[8];
  const float* W3_rel  = (const float*)d_in[9];
  const float* b3      = (const float*)d_in[10];
  const float* W3_root = (const float*)d_in[11];
  const float* pool_w  = (const float*)d_in[12];
  const float* Wl1     = (const float*)d_in[13];
  const float* bl1     = (const float*)d_in[14];
  const float* Wl2     = (const float*)d_in[15];
  const float* bl2     = (const float*)d_in[16];
  const float* Wl3     = (const float*)d_in[17];
  const float* bl3     = (const float*)d_in[18];
  float* out = (float*)d_out;

  // workspace layout
  char* w = (char*)d_ws;
  size_t off = 0;
  auto alloc = [&](size_t bytes) -> char* {
    off = (off + 255) & ~(size_t)255;
    char* p = w + off;
    off += bytes;
    return p;
  };
  int* deg1     = (int*)alloc((NB + 4096) * 4);   // +pad for exscan int4 tiles
  int* rs1      = (int*)alloc((NB + 1) * 4);
  int* cursor1  = (int*)alloc(NB * 4);
  int* csr1     = (int*)alloc((size_t)EE * 4);
  int* csr3     = (int*)alloc((size_t)EE * 4);
  int* new_id   = (int*)alloc(NB * 4);
  int* perm     = (int*)alloc(N1 * 4);
  int* rows3    = (int*)alloc(N1P * 4);
  int* rowe3    = (int*)alloc(N1P * 4);
  _Float16* wh1 = (_Float16*)alloc(128 * 128 * 2);
  _Float16* wl1 = (_Float16*)alloc(128 * 128 * 2);
  _Float16* wh2 = (_Float16*)alloc(128 * 256 * 2);
  _Float16* wl2 = (_Float16*)alloc(128 * 256 * 2);
  _Float16* wh3 = (_Float16*)alloc(128 * 256 * 2);
  _Float16* wl3 = (_Float16*)alloc(128 * 256 * 2);
  float* bufA   = (float*)alloc((size_t)NB * HH * 4);  // h1, then h3 (padded rows)
  float* bufB   = (float*)alloc((size_t)NB * HH * 4);  // h2, then h4 (padded rows)
  float* score  = (float*)alloc(NB * 4);
  float* pm1    = (float*)alloc(BG * 32 * HH * 4);
  float* ps1    = (float*)alloc(BG * 32 * HH * 4);
  float* pm2    = (float*)alloc(BG * 26 * HH * 4);
  float* ps2    = (float*)alloc(BG * 26 * HH * 4);
  float* pm3    = (float*)alloc(BG * 26 * HH * 4);
  float* ps3    = (float*)alloc(BG * 26 * HH * 4);
  if (off > ws_size) return;  // workspace too small: fail visibly

  const int TB = 256;
  const int egrid = (EE + TB - 1) / TB;

  // prep: weight split + deg1/new_id/rows3/rowe3 init (no separate memsets)
  prep_kernel<<<(128 * 128 + 2 * 128 * 256 + TB - 1) / TB, TB, 0, stream>>>(
      W1_rel, W1_root, W2_rel, W2_root, W3_rel, W3_root, wh1, wl1, wh2, wl2, wh3, wl3,
      deg1, new_id, rows3, rowe3);

  // CSR1 (src -> dst)
  deg_kernel<<<egrid, TB, 0, stream>>>(dst, deg1, EE);
  exscan_kernel<<<1, 1024, 0, stream>>>(deg1, rs1, cursor1, NB);
  scatter_kernel<<<egrid, TB, 0, stream>>>(src, dst, cursor1, csr1, EE);

  // conv1: gather + GEMM + x1 pool fused (64-row tiles)
  conv_mfma<64, 64, 1, 0, 0><<<NB / 64, 512, 0, stream>>>(
      x, x, rs1, csr1, nullptr, nullptr, wh1, wl1, b1, bufA, NB, NB / 64, pm1, ps1,
      nullptr, nullptr);

  // conv2: gather + GEMM + score fused
  conv_mfma<128, 128, 0, 1, 0><<<NB / 64, 512, 0, stream>>>(
      bufA, bufA, rs1, csr1, nullptr, nullptr, wh2, wl2, b2, bufB, NB, NB / 64,
      nullptr, nullptr, pool_w, score);

  // topk (radix-select); h3 gather (f4, padded ids, + row-range preresolve)
  topk_kernel<<<BG, 256, 0, stream>>>(score, perm);
  h3_kernel<<<(N1 * 32 + TB - 1) / TB, TB, 0, stream>>>((const float4*)bufB, perm, score,
                                                        rs1, (float4*)bufA, new_id,
                                                        rows3, rowe3);
  // csr3 = new_id[csr1] (removes dependent hop from conv3 gather)
  remap_kernel<<<egrid, TB, 0, stream>>>(csr1, new_id, csr3, EE);
  pool2_kernel<<<BG * 26, 128, 0, stream>>>(bufA, pm2, ps2);

  // conv3: gather via pre-resolved rows3/rowe3 + csr3 + GEMM + x3 pool fused
  conv_mfma<128, 128, 2, 0, 2><<<N1P / 64, 512, 0, stream>>>(
      bufA, bufA, nullptr, csr3, rows3, rowe3, wh3, wl3, b3, bufB, N1P, N1P / 64, pm3, ps3,
      nullptr, nullptr);

  // pool finals + MLP head + log_softmax (fused)
  mlp_kernel<<<BG, 128, 0, stream>>>(pm1, ps1, pm2, ps2, pm3, ps3,
                                     Wl1, bl1, Wl2, bl2, Wl3, bl3, out);
}